// Round 1
// 117.747 us; speedup vs baseline: 1.0119x; 1.0119x over previous
//
#include <hip/hip_runtime.h>

// Q=32, S=25, L=64, F=256, H=64
// out[q,s,i,f] = sum_j softmax_j( sum_h tanh(Wq[q,i,h]*Wh[s,j,h]) ) * hs[s,j,f]
// Wq = (qs @ W^T + b) * 2*log2(e)  (pre-scaled: exp2 arg ready), Wh = hs @ W^T + b
// tanh(x) = 1 - 2/(1+exp2(2log2e*x)); per-row constant 64 drops under softmax.
// 4 h-terms share one v_rcp (exp2 arg clamped <= 30: d<=2^61, den<=2^122, safe).
// r7: combine stage was scalar (11 of 20 slots per 4-term body). Pack it over
// column pairs: exp2 results land in v2f halves {e_col0,e_col1}; all combine
// math becomes v_pk_add/fma/mul_f32. 40 -> 30 issue slots per 8 terms (-25%).
// total - attn - prep ~= 63-70us is FIXED harness overhead; optimize attn only.

#define NQ 32
#define NS 25
#define NL 64
#define NF 256
#define NH 64

#define K2LOG2E 2.8853900817779268f

typedef __attribute__((ext_vector_type(8))) short bf16x8;
typedef __attribute__((ext_vector_type(4))) float f32x4;
typedef __attribute__((ext_vector_type(2))) float v2f;

__device__ inline unsigned short f2bf(float x) {  // RNE
    union { float f; unsigned int u; } v; v.f = x;
    unsigned int r = v.u + 0x7fffu + ((v.u >> 16) & 1u);
    return (unsigned short)(r >> 16);
}

__device__ inline void cvt_hilo(float4 a, float4 b, bf16x8* hi, bf16x8* lo) {
    float x[8] = {a.x, a.y, a.z, a.w, b.x, b.y, b.z, b.w};
    bf16x8 h8, l8;
#pragma unroll
    for (int i = 0; i < 8; ++i) {
        union { float f; unsigned int u; } v; v.f = x[i];
        unsigned short hh = (unsigned short)(v.u >> 16);
        h8[i] = (short)hh;
        union { unsigned int u; float f; } hf; hf.u = (unsigned int)hh << 16;
        union { float f; unsigned int u; } rv; rv.f = x[i] - hf.f;
        l8[i] = (short)(unsigned short)(rv.u >> 16);
    }
    *hi = h8; *lo = l8;
}

// ---------------- prep kernel (unchanged: ~3-7us, not the bottleneck) ----
#define PROJ_BLOCKS 114
__global__ __launch_bounds__(256) void prep_kernel(
    const float* __restrict__ qs, const float* __restrict__ hs,
    const float* __restrict__ W, const float* __restrict__ b,
    float* __restrict__ Wqs, float* __restrict__ Whs,
    unsigned short* __restrict__ hsT)
{
    __shared__ unsigned short T[64 * 72];
    const int t = threadIdx.x;
    const int bid = blockIdx.x;

    if (bid < PROJ_BLOCKS) {
        const int w = t >> 6, lane = t & 63;
        const int m15 = lane & 15, quad = lane >> 4;
        const int r0 = bid * 32 + (w & 1) * 16;
        const int h0 = (w >> 1) * 32;
        const bool is_q = (r0 < 2048);
        const float* Xrow = is_q ? (qs + (size_t)(r0 + m15) * NF)
                                 : (hs + (size_t)(r0 - 2048 + m15) * NF);
        f32x4 acc[2] = {(f32x4){0.f,0.f,0.f,0.f}, (f32x4){0.f,0.f,0.f,0.f}};

#pragma unroll 2
        for (int kk = 0; kk < 8; ++kk) {
            const int f0 = kk * 32 + quad * 8;
            bf16x8 xhi, xlo;
            cvt_hilo(*(const float4*)(Xrow + f0), *(const float4*)(Xrow + f0 + 4),
                     &xhi, &xlo);
#pragma unroll
            for (int nt = 0; nt < 2; ++nt) {
                const float* Wrow = W + (size_t)(h0 + nt * 16 + m15) * NF + f0;
                bf16x8 whi, wlo;
                cvt_hilo(*(const float4*)(Wrow), *(const float4*)(Wrow + 4),
                         &whi, &wlo);
                acc[nt] = __builtin_amdgcn_mfma_f32_16x16x32_bf16(xhi, whi, acc[nt], 0, 0, 0);
                acc[nt] = __builtin_amdgcn_mfma_f32_16x16x32_bf16(xhi, wlo, acc[nt], 0, 0, 0);
                acc[nt] = __builtin_amdgcn_mfma_f32_16x16x32_bf16(xlo, whi, acc[nt], 0, 0, 0);
            }
        }
#pragma unroll
        for (int nt = 0; nt < 2; ++nt) {
            const int h = h0 + nt * 16 + m15;
            const float bias = b[h];
#pragma unroll
            for (int r = 0; r < 4; ++r) {
                const int row = r0 + quad * 4 + r;
                const float v = acc[nt][r] + bias;
                if (is_q) Wqs[(size_t)row * NH + h] = v * K2LOG2E;
                else      Whs[(size_t)(row - 2048) * NH + h] = v;
            }
        }
    } else {
        const int b2 = bid - PROJ_BLOCKS;
        const int s = b2 >> 2;
        const int f0 = (b2 & 3) * 64;
        const float4* h4p = (const float4*)(hs + (size_t)s * NL * NF);
#pragma unroll
        for (int u = 0; u < 4; ++u) {
            int idx = t + 256 * u;
            int j = idx >> 4, fq = idx & 15;
            float4 v = h4p[j * 64 + (f0 >> 2) + fq];
            T[(4 * fq + 0) * 72 + j] = f2bf(v.x);
            T[(4 * fq + 1) * 72 + j] = f2bf(v.y);
            T[(4 * fq + 2) * 72 + j] = f2bf(v.z);
            T[(4 * fq + 3) * 72 + j] = f2bf(v.w);
        }
        __syncthreads();
#pragma unroll
        for (int u = 0; u < 2; ++u) {
            int idx = t + 256 * u;
            int fl = idx >> 3, jg = idx & 7;
            uint4 v = *(const uint4*)&T[fl * 72 + jg * 8];
            *(uint4*)&hsT[(size_t)(s * 256 + f0 + fl) * 64 + jg * 8] = v;
        }
    }
}

// 8 terms (4 h-values x 2 columns): combine fully packed over the column pair.
// sum accumulates {col0, col1} contributions of sum_h 1/(1+exp2(x)).
__device__ inline void score8(v2f alo, v2f ahi, float4 b0, float4 b1, v2f* sum) {
    const v2f vcl = {30.f, 30.f};
    v2f xlo0 = __builtin_elementwise_min(alo * (v2f){b0.x, b0.y}, vcl);
    v2f xhi0 = __builtin_elementwise_min(ahi * (v2f){b0.z, b0.w}, vcl);
    v2f xlo1 = __builtin_elementwise_min(alo * (v2f){b1.x, b1.y}, vcl);
    v2f xhi1 = __builtin_elementwise_min(ahi * (v2f){b1.z, b1.w}, vcl);
    // E_h = {e for col0, e for col1} -> all combine math is v_pk_*_f32
    v2f E0 = { __builtin_amdgcn_exp2f(xlo0[0]), __builtin_amdgcn_exp2f(xlo1[0]) };
    v2f E1 = { __builtin_amdgcn_exp2f(xlo0[1]), __builtin_amdgcn_exp2f(xlo1[1]) };
    v2f E2 = { __builtin_amdgcn_exp2f(xhi0[0]), __builtin_amdgcn_exp2f(xhi1[0]) };
    v2f E3 = { __builtin_amdgcn_exp2f(xhi0[1]), __builtin_amdgcn_exp2f(xhi1[1]) };
    v2f S01 = E0 + E1, S23 = E2 + E3;
    v2f D01 = __builtin_elementwise_fma(E0, E1, S01) + (v2f){1.f, 1.f};
    v2f D23 = __builtin_elementwise_fma(E2, E3, S23) + (v2f){1.f, 1.f};
    v2f U01 = S01 + (v2f){2.f, 2.f};
    v2f U23 = S23 + (v2f){2.f, 2.f};
    v2f NUM = __builtin_elementwise_fma(U01, D23, U23 * D01);
    v2f PROD = D01 * D23;
    v2f R = { __builtin_amdgcn_rcpf(PROD[0]), __builtin_amdgcn_rcpf(PROD[1]) };
    *sum = __builtin_elementwise_fma(NUM, R, *sum);
}

// ---------------- fused attention kernel ----------------
// Grid 3200: (q, s, quarter). Block: 16 i-rows x 64 j. 256 threads.
// LDS: A f32 [16][68] @0 (4352B) | B f32 [64][68] @4352B (17408B) = 21760B -> 7 blk/CU
//      att bf16 [16][72] overlaps A after scores (barrier-guarded).
#define AS 68
#define B_OFF 1088          // floats (16*68)
#define SMEMF 5440          // 21760 B

__global__ __launch_bounds__(256, 7) void attn_kernel(
    const float* __restrict__ Wqs, const float* __restrict__ Whs,
    const unsigned short* __restrict__ hsT, float* __restrict__ out)
{
    __shared__ float smem[SMEMF];
    const int t = threadIdx.x;
    const int bid = blockIdx.x;
    const int qt = bid & 3;
    const int s = (bid >> 2) % NS;
    const int q = bid / (4 * NS);

    // ---- stage A (16x64) and B (64x64), row-major stride 68 ----
    {
        const float4* a4 = (const float4*)(Wqs + ((size_t)q * NL + qt * 16) * NH);
        const float4* b4 = (const float4*)(Whs + (size_t)s * NL * NH);
        {
            int i = t >> 4, g = t & 15;
            *(float4*)&smem[i * AS + 4 * g] = a4[t];
        }
#pragma unroll
        for (int u = 0; u < 4; ++u) {
            int idx = t + 256 * u;
            int j = idx >> 4, g = idx & 15;
            *(float4*)&smem[B_OFF + j * AS + 4 * g] = b4[idx];
        }
    }
    __syncthreads();

    // ---- scores: row i = t>>4, col pairs (jn,jn+16) and (jn+32,jn+48) ----
    const int irow = t >> 4;
    const int jn = t & 15;
    v2f sumA = {0.f, 0.f}, sumB = {0.f, 0.f};
    {
        const float* Ab = &smem[irow * AS];
        const float* Bb = &smem[B_OFF + jn * AS];

#pragma unroll 4
        for (int h4 = 0; h4 < 16; ++h4) {
            float4 av = *(const float4*)(Ab + 4 * h4);
            v2f alo = {av.x, av.y}, ahi = {av.z, av.w};
            float4 b0 = *(const float4*)(Bb + 4 * h4);
            float4 b1 = *(const float4*)(Bb + 16 * AS + 4 * h4);
            score8(alo, ahi, b0, b1, &sumA);
            float4 b2 = *(const float4*)(Bb + 32 * AS + 4 * h4);
            float4 b3 = *(const float4*)(Bb + 48 * AS + 4 * h4);
            score8(alo, ahi, b2, b3, &sumB);
        }
    }
    __syncthreads();  // all A/B reads complete before att overwrites A region

    // ---- in-wave softmax over j (min-form: score = -2*sum + const) ----
    {
        float sum[4] = {sumA[0], sumA[1], sumB[0], sumB[1]};  // cols jn+16*jj
        float mn = fminf(fminf(sum[0], sum[1]), fminf(sum[2], sum[3]));
        mn = fminf(mn, __shfl_xor(mn, 1));
        mn = fminf(mn, __shfl_xor(mn, 2));
        mn = fminf(mn, __shfl_xor(mn, 4));
        mn = fminf(mn, __shfl_xor(mn, 8));
        float p[4];
        float d = 0.f;
#pragma unroll
        for (int jj = 0; jj < 4; ++jj) {
            p[jj] = __builtin_amdgcn_exp2f((mn - sum[jj]) * K2LOG2E);
            d += p[jj];
        }
        d += __shfl_xor(d, 1);
        d += __shfl_xor(d, 2);
        d += __shfl_xor(d, 4);
        d += __shfl_xor(d, 8);
        const float inv = __builtin_amdgcn_rcpf(d);
        unsigned short* att = (unsigned short*)smem;  // [16][72] bf16 over dead A
#pragma unroll
        for (int jj = 0; jj < 4; ++jj)
            att[irow * 72 + jn + 16 * jj] = f2bf(p[jj] * inv);
    }
    __syncthreads();

    // ---- PV via bf16 MFMA: [16 x 64j] @ [64j x 256f]; wave wv -> f-tiles wv*4.. ----
    const int lane = t & 63;
    const int wv = t >> 6;
    const int m15 = lane & 15;
    const int quad = lane >> 4;

    bf16x8 afr[2];  // A[m=lane&15][k=quad*8+idx]
#pragma unroll
    for (int k = 0; k < 2; ++k)
        afr[k] = *(const bf16x8*)((const char*)smem + m15 * 144 + k * 64 + quad * 16);

    const unsigned short* hsTs = hsT + (size_t)s * NF * NL;
    f32x4 acc[4];
#pragma unroll
    for (int n = 0; n < 4; ++n) acc[n] = (f32x4){0.f, 0.f, 0.f, 0.f};

#pragma unroll
    for (int k = 0; k < 2; ++k) {
        bf16x8 bfr[4];  // B[k][n=lane&15]: hsT row f, 8 consecutive j
#pragma unroll
        for (int n = 0; n < 4; ++n)
            bfr[n] = *(const bf16x8*)(hsTs
                        + (size_t)((wv * 4 + n) * 16 + m15) * 64 + k * 32 + quad * 8);
#pragma unroll
        for (int n = 0; n < 4; ++n)
            acc[n] = __builtin_amdgcn_mfma_f32_16x16x32_bf16(afr[k], bfr[n], acc[n], 0, 0, 0);
    }

    // C layout: col(f) = lane&15, row(i) = quad*4 + reg
    const size_t obase = ((size_t)(q * NS + s) * NL + qt * 16) * NF;
#pragma unroll
    for (int n = 0; n < 4; ++n)
#pragma unroll
        for (int r = 0; r < 4; ++r)
            out[obase + (size_t)(quad * 4 + r) * NF + (wv * 4 + n) * 16 + m15] = acc[n][r];
}

extern "C" void kernel_launch(void* const* d_in, const int* in_sizes, int n_in,
                              void* d_out, int out_size, void* d_ws, size_t ws_size,
                              hipStream_t stream) {
    const float* qs = (const float*)d_in[0];
    const float* hs = (const float*)d_in[1];
    const float* W  = (const float*)d_in[2];
    const float* b  = (const float*)d_in[3];
    float* out = (float*)d_out;

    float* Wqs = (float*)d_ws;                         // 131072 f
    float* Whs = Wqs + NQ * NL * NH;                   // 102400 f
    unsigned short* hsT = (unsigned short*)(Whs + NS * NL * NH);  // 409600 bf16

    prep_kernel<<<PROJ_BLOCKS + NS * 4, 256, 0, stream>>>(qs, hs, W, b, Wqs, Whs, hsT);
    attn_kernel<<<NQ * NS * 4, 256, 0, stream>>>(Wqs, Whs, hsT, out);
}